// Round 3
// baseline (69.416 us; speedup 1.0000x reference)
//
#include <hip/hip_runtime.h>
#include <math.h>

#define PI_F   3.14159265358979f
#define PIO32  0.0981747704246810f   // pi/32

// cos(pi*q/32), sin(pi*q/32), q = 0..31 (fp32-accurate literals; with
// compile-time indices under full unroll these fold to immediates).
constexpr float CT[32] = {
  1.0f,          0.995184727f,  0.980785280f,  0.956940336f,
  0.923879533f,  0.881921264f,  0.831469612f,  0.773010453f,
  0.707106781f,  0.634393284f,  0.555570233f,  0.471396737f,
  0.382683432f,  0.290284677f,  0.195090322f,  0.0980171403f,
  0.0f,         -0.0980171403f, -0.195090322f, -0.290284677f,
 -0.382683432f, -0.471396737f, -0.555570233f, -0.634393284f,
 -0.707106781f, -0.773010453f, -0.831469612f, -0.881921264f,
 -0.923879533f, -0.956940336f, -0.980785280f, -0.995184727f };
constexpr float ST[32] = {
  0.0f,          0.0980171403f, 0.195090322f,  0.290284677f,
  0.382683432f,  0.471396737f,  0.555570233f,  0.634393284f,
  0.707106781f,  0.773010453f,  0.831469612f,  0.881921264f,
  0.923879533f,  0.956940336f,  0.980785280f,  0.995184727f,
  1.0f,          0.995184727f,  0.980785280f,  0.956940336f,
  0.923879533f,  0.881921264f,  0.831469612f,  0.773010453f,
  0.707106781f,  0.634393284f,  0.555570233f,  0.471396737f,
  0.382683432f,  0.290284677f,  0.195090322f,  0.0980171403f };

struct Dim {
  float K;         // (-1)^{p*} * sin(pi * dstar)   (shared numerator)
  float Cr, Ci;    // cis((31pi/32) * sp)           (global unit phase)
  float sth, cth;  // sincos((pi/32) * sp)          (denominator tables)
  float spole;     // accurate sin((pi/32) * dstar) (pole denominator)
  int   pstar;     // nearest grid line
};

__device__ inline Dim dimcalc(float sp) {
  Dim d;
  const float ps = rintf(sp);
  d.pstar = (int)ps;
  float dstar = sp - ps;                 // EXACT in fp32 (Sterbenz)
  if (dstar == 0.0f) dstar = 1e-10f;     // removable singularity: ratio -> 32
  sincosf(sp * PIO32, &d.sth, &d.cth);
  float sd, cd;
  sincosf(PI_F * dstar, &sd, &cd);       // |arg| <= pi/2: accurate fast path
  const float par = (d.pstar & 1) ? -1.0f : 1.0f;
  d.K = par * sd;
  // C = cis(pi*sp - theta) = par*(cd + i sd)*(cth - i sth)
  d.Cr = par * fmaf(cd, d.cth, sd * d.sth);
  d.Ci = par * fmaf(sd, d.cth, -cd * d.sth);
  // sin(x) = x*(1 + x^2*(-1/6 + x^2/120)), |x| <= pi/64: rel err ~ 3e-12
  const float x = dstar * PIO32;
  const float x2 = x * x;
  d.spole = x * fmaf(x2, fmaf(x2, 0.00833333333f, -0.166666667f), 1.0f);
  return d;
}

// One fused kernel: out[b,n] = (1/1024) * Re( C0*C1 * sum_p H_p sum_q y[p,q] G_q )
// 4 lanes per sample point; lane h owns rows p = 8h .. 8h+7.
__global__ __launch_bounds__(256) void fourier_interp_kernel(
    const float* __restrict__ y, const float* __restrict__ xnew,
    float* __restrict__ out) {
  const int tid = threadIdx.x;
  const int gid = blockIdx.x * 256 + tid;
  const int h  = gid & 3;
  const int pt = gid >> 2;            // 0..32767
  const int b  = pt >> 12;

  const float2 x2v = ((const float2*)xnew)[pt];
  const Dim d0 = dimcalc(x2v.x * 31.0f);   // rows (i / p)
  const Dim d1 = dimcalc(x2v.y * 31.0f);   // cols (j / q)

  // G_q = K1 * r_q * cis(pi*q/32), q = 0..31 (compile-time q -> literal tables)
  float Gr[32], Gi[32];
#pragma unroll
  for (int q = 0; q < 32; ++q) {
    float s = fmaf(d1.sth, CT[q], -d1.cth * ST[q]);  // sin((pi/32)(sp1 - q))
    if (q == d1.pstar) s = d1.spole;                 // accurate pole denom
    const float t = d1.K * __builtin_amdgcn_rcpf(s);
    Gr[q] = t * CT[q];
    Gi[q] = t * ST[q];
  }

  // H_p for p = 8h + pp: cis(pi*p/32) = cis(pi*h/4) * cis(pi*pp/32)
  const float e4r = (h == 0) ? 1.f : (h == 1) ? 0.707106781f
                  : (h == 2) ? 0.f : -0.707106781f;
  const float e4i = (h == 0) ? 0.f : (h == 1) ? 0.707106781f
                  : (h == 2) ? 1.f : 0.707106781f;
  const int p0 = h * 8;
  float Hr[8], Hi[8];
#pragma unroll
  for (int pp = 0; pp < 8; ++pp) {
    const float Tr = fmaf(e4r, CT[pp], -e4i * ST[pp]);
    const float Ti = fmaf(e4r, ST[pp],  e4i * CT[pp]);
    float s = fmaf(d0.sth, Tr, -d0.cth * Ti);        // sin((pi/32)(sp0 - p))
    if (p0 + pp == d0.pstar) s = d0.spole;
    const float t = d0.K * __builtin_amdgcn_rcpf(s);
    Hr[pp] = t * Tr;
    Hi[pp] = t * Ti;
  }

  // Main: S_p = sum_q y[p,q]*G_q (real*complex, 2 FMA/elem);  Z = sum_p H_p*S_p
  const float4* yr = (const float4*)(y + b * 1024 + p0 * 32);
  float Zr = 0.f, Zi = 0.f;
#pragma unroll
  for (int pp = 0; pp < 8; ++pp) {
    float SrA = 0.f, SrB = 0.f, SiA = 0.f, SiB = 0.f;
#pragma unroll
    for (int q4 = 0; q4 < 8; ++q4) {
      const float4 v = yr[pp * 8 + q4];
      SrA = fmaf(v.x, Gr[4 * q4 + 0], SrA); SiA = fmaf(v.x, Gi[4 * q4 + 0], SiA);
      SrB = fmaf(v.y, Gr[4 * q4 + 1], SrB); SiB = fmaf(v.y, Gi[4 * q4 + 1], SiB);
      SrA = fmaf(v.z, Gr[4 * q4 + 2], SrA); SiA = fmaf(v.z, Gi[4 * q4 + 2], SiA);
      SrB = fmaf(v.w, Gr[4 * q4 + 3], SrB); SiB = fmaf(v.w, Gi[4 * q4 + 3], SiB);
    }
    const float Sr = SrA + SrB;
    const float Si = SiA + SiB;
    Zr = fmaf(Hr[pp], Sr, Zr); Zr = fmaf(-Hi[pp], Si, Zr);
    Zi = fmaf(Hr[pp], Si, Zi); Zi = fmaf(Hi[pp], Sr, Zi);
  }

  // Combine the 4-lane group, apply the unit phases, take Re, scale.
  Zr += __shfl_xor(Zr, 1); Zr += __shfl_xor(Zr, 2);
  Zi += __shfl_xor(Zi, 1); Zi += __shfl_xor(Zi, 2);
  const float Cr = fmaf(d0.Cr, d1.Cr, -d0.Ci * d1.Ci);
  const float Ci = fmaf(d0.Cr, d1.Ci,  d0.Ci * d1.Cr);
  const float res = fmaf(Cr, Zr, -Ci * Zi) * (1.0f / 1024.0f);

  // Pack 16 results into lanes 0..15 of each wave for a coalesced 64B store.
  const int l = tid & 63;
  const float packed = __shfl(res, (l & 15) * 4);
  if (l < 16) {
    const int wbase = (blockIdx.x * 256 + (tid & ~63)) >> 2;
    out[wbase + l] = packed;
  }
}

extern "C" void kernel_launch(void* const* d_in, const int* in_sizes, int n_in,
                              void* d_out, int out_size, void* d_ws, size_t ws_size,
                              hipStream_t stream) {
  const float* y    = (const float*)d_in[0];   // (8, 32, 32) f32
  const float* xnew = (const float*)d_in[1];   // (8, 64, 64, 2) f32
  float* out = (float*)d_out;                  // (8, 64, 64) f32
  (void)d_ws; (void)ws_size;                   // workspace no longer needed

  // 8 * 4096 points * 4 lanes / 256 threads = 512 blocks
  hipLaunchKernelGGL(fourier_interp_kernel, dim3(512), dim3(256), 0, stream,
                     xnew ? y : y, xnew, out);
}